// Round 4
// baseline (104.108 us; speedup 1.0000x reference)
//
#include <hip/hip_runtime.h>
#include <math.h>

// Problem constants
#define BB 32
#define TT 4096
#define DD 512
#define SS 256
#define NCH 64            // chunks per batch
#define CR 64             // rows per chunk (NCH*CR == TT)
static constexpr float INV_SCALE = 10.0f;   // 1/0.1

// ---------------------------------------------------------------------------
// Kernel 1: q = silu(t_star*W1+b1) @ W2 + b2.
// grid = B*8 blocks (b, jg); block 512 = 64 outputs x 8 k-groups.
// ---------------------------------------------------------------------------
__global__ __launch_bounds__(512) void k_q(
    const float* __restrict__ t_star, const float* __restrict__ W1,
    const float* __restrict__ b1, const float* __restrict__ W2,
    const float* __restrict__ b2, float* __restrict__ q) {
  const int b   = blockIdx.x >> 3;
  const int jg  = blockIdx.x & 7;
  const int tid = threadIdx.x;
  const int di  = tid & 63;
  const int kg  = tid >> 6;
  __shared__ float h[DD];
  __shared__ float red[8][64];
  {
    float x = t_star[b] * W1[tid] + b1[tid];
    h[tid] = x / (1.0f + __expf(-x));     // silu
  }
  __syncthreads();
  const float* w = W2 + jg * 64 + di;
  float acc = 0.0f;
#pragma unroll 8
  for (int kk = 0; kk < 64; ++kk) {
    const int k = kg * 64 + kk;
    acc += h[k] * w[(size_t)k * DD];
  }
  red[kg][di] = acc;
  __syncthreads();
  if (tid < 64) {
    float s = 0.0f;
#pragma unroll
    for (int g = 0; g < 8; ++g) s += red[g][tid];
    q[b * DD + jg * 64 + tid] = s + b2[jg * 64 + tid];
  }
}

// ---------------------------------------------------------------------------
// Kernel 2: wave-independent flash pooling. Each WAVE owns one chunk of 64
// rows; online softmax (m,l) + pooled partial entirely in registers.
// No __syncthreads, no LDS. Double-buffered 8-row groups.
// Lane holds ctx[.., lane*4..lane*4+3] and ctx[.., 256+lane*4 ..].
// ---------------------------------------------------------------------------
__device__ __forceinline__ void load_group(
    const float* cbase, int g, int lane, float4 (&d0)[8], float4 (&d1)[8]) {
  const float4* cp = (const float4*)(cbase + (size_t)g * 8 * DD);
#pragma unroll
  for (int r = 0; r < 8; ++r) {
    d0[r] = cp[r * 128 + lane];
    d1[r] = cp[r * 128 + 64 + lane];
  }
}

__device__ __forceinline__ void compute_group(
    const float4 (&d0)[8], const float4 (&d1)[8], int g,
    const float4 q0, const float4 q1, float tb,
    float& m, float& l, float4& p0, float4& p1) {
  float s[8];
#pragma unroll
  for (int r = 0; r < 8; ++r) {
    float a = d0[r].x * q0.x + d0[r].y * q0.y + d0[r].z * q0.z + d0[r].w * q0.w +
              d1[r].x * q1.x + d1[r].y * q1.y + d1[r].z * q1.z + d1[r].w * q1.w;
#pragma unroll
    for (int off = 32; off > 0; off >>= 1) a += __shfl_xor(a, off);
    s[r] = a + __shfl(tb, g * 8 + r);
  }
  float gm = s[0];
#pragma unroll
  for (int r = 1; r < 8; ++r) gm = fmaxf(gm, s[r]);
  const float nm = fmaxf(m, gm);
  const float sc = __expf(m - nm);   // first group: exp(-inf)=0, p==0 anyway
  m = nm;
  l *= sc;
  p0.x *= sc; p0.y *= sc; p0.z *= sc; p0.w *= sc;
  p1.x *= sc; p1.y *= sc; p1.z *= sc; p1.w *= sc;
#pragma unroll
  for (int r = 0; r < 8; ++r) {
    const float e = __expf(s[r] - m);
    l += e;
    p0.x += e * d0[r].x; p0.y += e * d0[r].y;
    p0.z += e * d0[r].z; p0.w += e * d0[r].w;
    p1.x += e * d1[r].x; p1.y += e * d1[r].y;
    p1.z += e * d1[r].z; p1.w += e * d1[r].w;
  }
}

__global__ __launch_bounds__(256) void k_fused(
    const float* __restrict__ ctx, const float* __restrict__ q,
    const float* __restrict__ t_star, const float* __restrict__ t_ctx,
    float* __restrict__ part_pool,    // [B*NCH*DD]
    float* __restrict__ part_ms) {    // [B*NCH*2]  (m_c, l_c)
  const int wid  = threadIdx.x >> 6;
  const int lane = threadIdx.x & 63;
  const int wg   = blockIdx.x * 4 + wid;   // global wave id
  const int b    = wg >> 6;                // / NCH
  const int c    = wg & 63;                // % NCH

  const float4* qp = (const float4*)(q + b * DD);
  const float4 q0 = qp[lane];
  const float4 q1 = qp[64 + lane];
  const float ts = t_star[b];
  const float tb = -fabsf(ts - t_ctx[b * TT + c * CR + lane]) * INV_SCALE;

  const float* cbase = ctx + ((size_t)b * TT + (size_t)c * CR) * DD;

  float m = -INFINITY, l = 0.0f;
  float4 p0 = {0, 0, 0, 0}, p1 = {0, 0, 0, 0};

  float4 A0[8], A1[8], B0[8], B1[8];
  load_group(cbase, 0, lane, A0, A1);
  load_group(cbase, 1, lane, B0, B1);
  compute_group(A0, A1, 0, q0, q1, tb, m, l, p0, p1);
  load_group(cbase, 2, lane, A0, A1);
  compute_group(B0, B1, 1, q0, q1, tb, m, l, p0, p1);
  load_group(cbase, 3, lane, B0, B1);
  compute_group(A0, A1, 2, q0, q1, tb, m, l, p0, p1);
  load_group(cbase, 4, lane, A0, A1);
  compute_group(B0, B1, 3, q0, q1, tb, m, l, p0, p1);
  load_group(cbase, 5, lane, B0, B1);
  compute_group(A0, A1, 4, q0, q1, tb, m, l, p0, p1);
  load_group(cbase, 6, lane, A0, A1);
  compute_group(B0, B1, 5, q0, q1, tb, m, l, p0, p1);
  load_group(cbase, 7, lane, B0, B1);
  compute_group(A0, A1, 6, q0, q1, tb, m, l, p0, p1);
  compute_group(B0, B1, 7, q0, q1, tb, m, l, p0, p1);

  float4* pp = (float4*)(part_pool + ((size_t)b * NCH + c) * DD);
  pp[lane] = p0;
  pp[64 + lane] = p1;
  if (lane == 0) {
    part_ms[(b * NCH + c) * 2 + 0] = m;
    part_ms[(b * NCH + c) * 2 + 1] = l;
  }
}

// ---------------------------------------------------------------------------
// Kernel 3: exact online-softmax merge of chunk partials + Wout epilogue.
// grid = B*2 (b, jg); block 256.
// ---------------------------------------------------------------------------
__global__ __launch_bounds__(256) void k_final(
    const float* __restrict__ part_pool, const float* __restrict__ part_ms,
    const float* __restrict__ Wout, const float* __restrict__ bout,
    float* __restrict__ out) {
  const int b   = blockIdx.x >> 1;
  const int jg  = blockIdx.x & 1;
  const int tid = threadIdx.x;
  __shared__ float pool[DD];
  __shared__ float scl[NCH];

  float M = -INFINITY;
  for (int c = 0; c < NCH; ++c) M = fmaxf(M, part_ms[(b * NCH + c) * 2]);
  float Z = 0.0f;
  for (int c = 0; c < NCH; ++c)
    Z += __expf(part_ms[(b * NCH + c) * 2] - M) * part_ms[(b * NCH + c) * 2 + 1];
  const float invZ = 1.0f / Z;
  if (tid < NCH) scl[tid] = __expf(part_ms[(b * NCH + tid) * 2] - M);
  __syncthreads();

  for (int d = tid; d < DD; d += 256) {
    float acc = 0.0f;
#pragma unroll 8
    for (int c = 0; c < NCH; ++c)
      acc += scl[c] * part_pool[((size_t)b * NCH + c) * DD + d];
    pool[d] = acc * invZ;
  }
  __syncthreads();

  const int j = jg * 256 + tid;
  float o = bout[j];
#pragma unroll 8
  for (int d = 0; d < DD; ++d) o += pool[d] * Wout[(size_t)d * DD + j];
  if (j < SS) out[b * SS + j] = o;                        // mu
  else        out[BB * SS + b * SS + (j - SS)] = o;       // log_sigma
}

// ---------------------------------------------------------------------------
extern "C" void kernel_launch(void* const* d_in, const int* in_sizes, int n_in,
                              void* d_out, int out_size, void* d_ws, size_t ws_size,
                              hipStream_t stream) {
  const float* ctx    = (const float*)d_in[0];   // (B,T,D)
  const float* t_star = (const float*)d_in[1];   // (B,)
  const float* t_ctx  = (const float*)d_in[2];   // (B,T,1)
  const float* W1     = (const float*)d_in[3];   // (1,D)
  const float* b1     = (const float*)d_in[4];   // (D,)
  const float* W2     = (const float*)d_in[5];   // (D,D)
  const float* b2     = (const float*)d_in[6];   // (D,)
  const float* Wout   = (const float*)d_in[7];   // (D,2S)
  const float* bout   = (const float*)d_in[8];   // (2S,)
  float* out = (float*)d_out;

  float* ws = (float*)d_ws;
  float* q         = ws;                                   // B*D
  float* part_pool = q + (size_t)BB * DD;                  // B*NCH*D
  float* part_ms   = part_pool + (size_t)BB * NCH * DD;    // B*NCH*2

  k_q<<<BB * 8, 512, 0, stream>>>(t_star, W1, b1, W2, b2, q);
  k_fused<<<BB * NCH / 4, 256, 0, stream>>>(ctx, q, t_star, t_ctx, part_pool, part_ms);
  k_final<<<BB * 2, 256, 0, stream>>>(part_pool, part_ms, Wout, bout, out);
}